// Round 4
// baseline (693.317 us; speedup 1.0000x reference)
//
#include <hip/hip_runtime.h>
#include <cmath>

// Diagonal linear recurrence y[l][h] = exp(tau[h])*y[l-1][h] + x[l][h]
// L=16384, H=1024, fp32.
//
// R4: fused single-pass chunked scan with ticket-ordered decoupled lookback.
//  - Each block owns one chunk of TC=16 rows (C=1024 chunks), chunk id via
//    atomic ticket (start-order => lookback can never deadlock regardless of
//    dispatch order / residency).
//  - Loads the whole chunk into registers ONCE (16 float4/thread), computes
//    the zero-carry local scan in place, publishes the chunk aggregate
//    (flag=1), resolves carry by window-batched lookback over predecessors
//    (aggregates, early-exit on an inclusive prefix flag=2), publishes its
//    own inclusive prefix (flag=2), then writes y = local + lam^(i+1)*carry.
//  - Traffic: x 64MB read (once), y 64MB write, agg/pref 8MB, vs 208MB for
//    the R3 three-pass version.

static constexpr int TC = 16;   // rows per chunk -> C = L/TC = 1024
static constexpr int W  = 4;    // lookback window (batched independent loads)

__global__ __launch_bounds__(256)
void li_fused(const float4* __restrict__ xv, const float4* __restrict__ tauv,
              float4* __restrict__ yv, int* __restrict__ ticket,
              int* __restrict__ flags, float4* __restrict__ agg,
              float4* __restrict__ pref, int HV)
{
    __shared__ int c_sh;
    const int t = threadIdx.x;                 // float4 column (4 channels)
    if (t == 0)
        c_sh = __hip_atomic_fetch_add(ticket, 1, __ATOMIC_RELAXED,
                                      __HIP_MEMORY_SCOPE_AGENT);
    __syncthreads();
    const int c = c_sh;                        // chunk id in start order

    const float4 tv = tauv[t];
    const float lx = expf(tv.x), ly = expf(tv.y),
                lz = expf(tv.z), lw = expf(tv.w);
    const float Tx = expf(tv.x * (float)TC), Ty = expf(tv.y * (float)TC),
                Tz = expf(tv.z * (float)TC), Tw = expf(tv.w * (float)TC);

    // ---- load whole chunk into registers (16 independent 16B loads) ----
    const size_t base = (size_t)c * TC * HV + t;
    float4 buf[TC];
#pragma unroll
    for (int i = 0; i < TC; ++i)
        buf[i] = xv[base + (size_t)i * HV];

    // ---- zero-carry local scan, in place ----
    float4 s = make_float4(0.f, 0.f, 0.f, 0.f);
#pragma unroll
    for (int i = 0; i < TC; ++i) {
        s.x = fmaf(lx, s.x, buf[i].x);
        s.y = fmaf(ly, s.y, buf[i].y);
        s.z = fmaf(lz, s.z, buf[i].z);
        s.w = fmaf(lw, s.w, buf[i].w);
        buf[i] = s;
    }
    // s == e_c (chunk-end value with zero carry-in)

    // ---- publish aggregate ----
    agg[(size_t)c * HV + t] = s;
    __syncthreads();   // each wave drains vmcnt before barrier => stores in L2
    if (t == 0)
        __hip_atomic_store(&flags[c], 1, __ATOMIC_RELEASE,
                           __HIP_MEMORY_SCOPE_AGENT);

    // ---- lookback: carry_in(c) = sum_{cc<c} lamT^(c-1-cc) * e_cc ----
    float4 carry = make_float4(0.f, 0.f, 0.f, 0.f);
    if (c > 0) {
        float4 m = make_float4(1.f, 1.f, 1.f, 1.f);
        int cc = c - 1;
        for (;;) {
            const int jmax = (cc + 1 < W) ? (cc + 1) : W;
            int f[W];
            bool ready;
            do {
                ready = true;
#pragma unroll
                for (int j = 0; j < W; ++j) {
                    if (j < jmax) {
                        f[j] = __hip_atomic_load(&flags[cc - j],
                                                 __ATOMIC_RELAXED,
                                                 __HIP_MEMORY_SCOPE_AGENT);
                        ready = ready && (f[j] != 0);
                    }
                }
                if (!ready) __builtin_amdgcn_s_sleep(8);
            } while (!ready);
            __builtin_amdgcn_fence(__ATOMIC_ACQUIRE, "agent");

            int jstop = jmax - 1;
            bool hit = false;
#pragma unroll
            for (int j = 0; j < W; ++j) {
                if (j < jmax && !hit && f[j] == 2) { jstop = j; hit = true; }
            }
            // batched independent value loads
            float4 v[W];
#pragma unroll
            for (int j = 0; j < W; ++j) {
                if (j <= jstop) {
                    const float4* src = (hit && j == jstop) ? pref : agg;
                    v[j] = src[(size_t)(cc - j) * HV + t];
                }
            }
#pragma unroll
            for (int j = 0; j < W; ++j) {
                if (j <= jstop) {
                    carry.x = fmaf(m.x, v[j].x, carry.x);
                    carry.y = fmaf(m.y, v[j].y, carry.y);
                    carry.z = fmaf(m.z, v[j].z, carry.z);
                    carry.w = fmaf(m.w, v[j].w, carry.w);
                    m.x *= Tx; m.y *= Ty; m.z *= Tz; m.w *= Tw;
                }
            }
            if (hit || (cc - jstop) == 0) break;   // prefix found or reached 0
            cc -= jstop + 1;
        }
    }

    // ---- publish inclusive prefix P = e_c + lamT*carry ----
    float4 P;
    P.x = fmaf(Tx, carry.x, s.x);
    P.y = fmaf(Ty, carry.y, s.y);
    P.z = fmaf(Tz, carry.z, s.z);
    P.w = fmaf(Tw, carry.w, s.w);
    pref[(size_t)c * HV + t] = P;
    __syncthreads();
    if (t == 0)
        __hip_atomic_store(&flags[c], 2, __ATOMIC_RELEASE,
                           __HIP_MEMORY_SCOPE_AGENT);

    // ---- outputs: y[cT+i] = buf[i] + lam^(i+1)*carry ----
    float4 pm = make_float4(lx, ly, lz, lw);
#pragma unroll
    for (int i = 0; i < TC; ++i) {
        float4 o;
        o.x = fmaf(pm.x, carry.x, buf[i].x);
        o.y = fmaf(pm.y, carry.y, buf[i].y);
        o.z = fmaf(pm.z, carry.z, buf[i].z);
        o.w = fmaf(pm.w, carry.w, buf[i].w);
        yv[base + (size_t)i * HV] = o;
        pm.x *= lx; pm.y *= ly; pm.z *= lz; pm.w *= lw;
    }
}

extern "C" void kernel_launch(void* const* d_in, const int* in_sizes, int n_in,
                              void* d_out, int out_size, void* d_ws, size_t ws_size,
                              hipStream_t stream) {
    const float* x   = (const float*)d_in[0];
    const float* tau = (const float*)d_in[1];
    float* y = (float*)d_out;

    const int H  = in_sizes[1];        // 1024
    const int L  = in_sizes[0] / H;    // 16384
    const int C  = L / TC;             // 1024
    const int HV = H / 4;              // 256 float4 columns

    // workspace layout
    int*    ticket = (int*)d_ws;
    int*    flags  = (int*)((char*)d_ws + 256);
    float4* agg    = (float4*)((char*)d_ws + 8192);            // C*H floats = 4MB
    float4* pref   = agg + (size_t)C * HV;                     // 4MB

    // zero ticket + flags (capturable async memset; 8KB)
    hipMemsetAsync(d_ws, 0, 8192, stream);

    li_fused<<<dim3(C), dim3(256), 0, stream>>>(
        (const float4*)x, (const float4*)tau, (float4*)y,
        ticket, flags, agg, pref, HV);
}

// Round 6
// 132.729 us; speedup vs baseline: 5.2236x; 5.2236x over previous
//
#include <hip/hip_runtime.h>
#include <cmath>

// Diagonal linear recurrence y[l][h] = exp(tau[h])*y[l-1][h] + x[l][h]
// L=16384, H=1024, fp32.
//
// R6 = R5 with the nontemporal-store type fixed (native ext_vector_type).
// Feed-forward 3-level chunked scan (no inter-block sync — R4's decoupled
// lookback serialized at ~1us per cross-XCD hop -> 600us).
//   K1 li_ends:  per-chunk (TC=16 rows) zero-carry aggregates e_c[h]  (4MB)
//   K2 li_pagg:  per-partition (P=16 chunks) aggregates pa_p[h]      (64KB)
//   K3 li_pscan: exclusive scan over the 64 partitions per channel   (tiny)
//   K4 li_out:   carry = partition carry + <=15 L2-hot chunk rows, then local
//                replay from x (L3-resident) with nontemporal y stores.

static constexpr int TC = 16;    // rows per chunk      -> C  = 1024
static constexpr int P  = 16;    // chunks per partition-> NP = 64

typedef float nt4 __attribute__((ext_vector_type(4)));  // for nontemporal st

__global__ __launch_bounds__(256)
void li_ends(const float4* __restrict__ xv, const float4* __restrict__ tauv,
             float4* __restrict__ ends, int HV) {
    const int t = threadIdx.x;           // float4 column
    const int c = blockIdx.x;            // chunk
    const float4 tv = tauv[t];
    const float lx = expf(tv.x), ly = expf(tv.y),
                lz = expf(tv.z), lw = expf(tv.w);

    const float4* xp = xv + (size_t)c * TC * HV + t;
    float4 buf[TC];
#pragma unroll
    for (int i = 0; i < TC; ++i)
        buf[i] = xp[(size_t)i * HV];     // 16 independent 16B loads

    float4 s = make_float4(0.f, 0.f, 0.f, 0.f);
#pragma unroll
    for (int i = 0; i < TC; ++i) {
        s.x = fmaf(lx, s.x, buf[i].x);
        s.y = fmaf(ly, s.y, buf[i].y);
        s.z = fmaf(lz, s.z, buf[i].z);
        s.w = fmaf(lw, s.w, buf[i].w);
    }
    ends[(size_t)c * HV + t] = s;
}

// pa[p][h] = sum_{j<P} lamT^(P-1-j) * ends[p*P+j][h]
__global__ __launch_bounds__(256)
void li_pagg(const float4* __restrict__ ends, const float4* __restrict__ tauv,
             float4* __restrict__ pa, int HV) {
    const int gid = blockIdx.x * 256 + threadIdx.x;   // 0..NP*HV-1
    const int t = gid % HV;                           // float4 column
    const int p = gid / HV;                           // partition
    const float4 tv = tauv[t];
    const float Tx = expf(tv.x * (float)TC), Ty = expf(tv.y * (float)TC),
                Tz = expf(tv.z * (float)TC), Tw = expf(tv.w * (float)TC);

    const float4* ep = ends + (size_t)p * P * HV + t;
    float4 buf[P];
#pragma unroll
    for (int j = 0; j < P; ++j)
        buf[j] = ep[(size_t)j * HV];

    float4 s = make_float4(0.f, 0.f, 0.f, 0.f);
#pragma unroll
    for (int j = 0; j < P; ++j) {
        s.x = fmaf(Tx, s.x, buf[j].x);
        s.y = fmaf(Ty, s.y, buf[j].y);
        s.z = fmaf(Tz, s.z, buf[j].z);
        s.w = fmaf(Tw, s.w, buf[j].w);
    }
    pa[(size_t)p * HV + t] = s;
}

// In-place: pa[p][h] -> exclusive carry prefix with factor lamTP = exp(P*TC*tau)
// (carry into partition p). Single block, 256 float4 lanes, NP serial steps.
__global__ __launch_bounds__(256)
void li_pscan(float4* __restrict__ pa, const float4* __restrict__ tauv,
              int HV, int NP) {
    const int t = threadIdx.x;
    const float4 tv = tauv[t];
    const float fP = (float)(P * TC);
    const float Px = expf(tv.x * fP), Py = expf(tv.y * fP),
                Pz = expf(tv.z * fP), Pw = expf(tv.w * fP);
    float4 c = make_float4(0.f, 0.f, 0.f, 0.f);
    for (int p0 = 0; p0 < NP; p0 += 16) {
        float4 v[16];
#pragma unroll
        for (int j = 0; j < 16; ++j)
            v[j] = pa[(size_t)(p0 + j) * HV + t];     // batched, independent
#pragma unroll
        for (int j = 0; j < 16; ++j) {
            const float4 a = v[j];
            v[j] = c;                                 // exclusive prefix
            c.x = fmaf(Px, c.x, a.x);
            c.y = fmaf(Py, c.y, a.y);
            c.z = fmaf(Pz, c.z, a.z);
            c.w = fmaf(Pw, c.w, a.w);
        }
#pragma unroll
        for (int j = 0; j < 16; ++j)
            pa[(size_t)(p0 + j) * HV + t] = v[j];
    }
}

__global__ __launch_bounds__(256)
void li_out(const float4* __restrict__ xv, const float4* __restrict__ tauv,
            const float4* __restrict__ ends, const float4* __restrict__ pc,
            float4* __restrict__ yv, int HV) {
    const int t = threadIdx.x;
    const int c = blockIdx.x;
    const int p = c / P;           // partition
    const int r = c % P;           // chunk index within partition
    const float4 tv = tauv[t];
    const float lx = expf(tv.x), ly = expf(tv.y),
                lz = expf(tv.z), lw = expf(tv.w);
    const float Tx = expf(tv.x * (float)TC), Ty = expf(tv.y * (float)TC),
                Tz = expf(tv.z * (float)TC), Tw = expf(tv.w * (float)TC);

    // ---- carry into chunk c: partition carry advanced over r chunk rows ----
    float4 carry = pc[(size_t)p * HV + t];
    {
        float4 v[P - 1];
        const float4* ep = ends + (size_t)p * P * HV + t;
#pragma unroll
        for (int j = 0; j < P - 1; ++j)
            if (j < r) v[j] = ep[(size_t)j * HV];     // L2-hot, batched
#pragma unroll
        for (int j = 0; j < P - 1; ++j) {
            if (j < r) {
                // carry(cc+1) = lamT*carry(cc) + e_cc
                carry.x = fmaf(Tx, carry.x, v[j].x);
                carry.y = fmaf(Ty, carry.y, v[j].y);
                carry.z = fmaf(Tz, carry.z, v[j].z);
                carry.w = fmaf(Tw, carry.w, v[j].w);
            }
        }
    }

    // ---- local replay seeded with carry ----
    const size_t base = (size_t)c * TC * HV + t;
    float4 buf[TC];
#pragma unroll
    for (int i = 0; i < TC; ++i)
        buf[i] = xv[base + (size_t)i * HV];

    float4 s = carry;
#pragma unroll
    for (int i = 0; i < TC; ++i) {
        s.x = fmaf(lx, s.x, buf[i].x);
        s.y = fmaf(ly, s.y, buf[i].y);
        s.z = fmaf(lz, s.z, buf[i].z);
        s.w = fmaf(lw, s.w, buf[i].w);
        buf[i] = s;
    }
    nt4* yn = (nt4*)yv;
#pragma unroll
    for (int i = 0; i < TC; ++i) {
        nt4 o = { buf[i].x, buf[i].y, buf[i].z, buf[i].w };
        __builtin_nontemporal_store(o, &yn[base + (size_t)i * HV]);
    }
}

extern "C" void kernel_launch(void* const* d_in, const int* in_sizes, int n_in,
                              void* d_out, int out_size, void* d_ws, size_t ws_size,
                              hipStream_t stream) {
    const float* x   = (const float*)d_in[0];
    const float* tau = (const float*)d_in[1];
    float* y = (float*)d_out;

    const int H  = in_sizes[1];        // 1024
    const int L  = in_sizes[0] / H;    // 16384
    const int C  = L / TC;             // 1024
    const int NP = C / P;              // 64
    const int HV = H / 4;              // 256 float4 columns

    float4* ends = (float4*)d_ws;                       // C*HV float4 = 4 MB
    float4* pa   = ends + (size_t)C * HV;               // NP*HV float4 = 64 KB

    const float4* xv   = (const float4*)x;
    const float4* tauv = (const float4*)tau;

    li_ends <<<dim3(C),             dim3(256), 0, stream>>>(xv, tauv, ends, HV);
    li_pagg <<<dim3(NP * HV / 256), dim3(256), 0, stream>>>(ends, tauv, pa, HV);
    li_pscan<<<dim3(1),             dim3(256), 0, stream>>>(pa, tauv, HV, NP);
    li_out  <<<dim3(C),             dim3(256), 0, stream>>>(xv, tauv, ends, pa,
                                                            (float4*)y, HV);
}

// Round 7
// 131.789 us; speedup vs baseline: 5.2608x; 1.0071x over previous
//
#include <hip/hip_runtime.h>
#include <hip/hip_cooperative_groups.h>
#include <cmath>

// Diagonal linear recurrence y[l][h] = exp(tau[h])*y[l-1][h] + x[l][h]
// L=16384, H=1024, fp32.
//
// R7: single cooperative kernel. Each block owns one TC=16-row chunk held in
// registers across two grid.sync()s, so x is read exactly once (R6's K4
// re-read 64MB from L3) and 3 kernel launches + gaps disappear.
//   phase1: local zero-carry scan in regs, publish chunk aggregate e_c (4MB)
//   sync
//   phase2: blocks 0..63 publish partition (P=16 chunks) aggregates pa (64KB)
//   sync
//   phase3: every block: carry = scan pa[0..p-1] (L2-hot, batch-8)
//           + advance over r in-partition chunk rows, write y (nontemporal).
// Fallback: R6's feed-forward 4-kernel path if cooperative launch can't go.

namespace cg = cooperative_groups;

static constexpr int TC = 16;    // rows per chunk      -> C  = 1024
static constexpr int P  = 16;    // chunks per partition-> NP = 64

typedef float nt4 __attribute__((ext_vector_type(4)));

__device__ inline float4 ntload(const float4* p) {
    nt4 v = __builtin_nontemporal_load((const nt4*)p);
    return make_float4(v.x, v.y, v.z, v.w);
}

__global__ __launch_bounds__(256, 4)   // cap VGPR at 128 -> 4 blocks/CU resident
void li_coop(const float4* __restrict__ xv, const float4* __restrict__ tauv,
             float4* __restrict__ yv, float4* __restrict__ ends,
             float4* __restrict__ pa, int HV, int NP)
{
    const int t = threadIdx.x;           // float4 column (4 channels)
    const int c = blockIdx.x;            // chunk

    const float4 tv = tauv[t];
    const float lx = expf(tv.x), ly = expf(tv.y),
                lz = expf(tv.z), lw = expf(tv.w);
    const float Tx = expf(tv.x * (float)TC), Ty = expf(tv.y * (float)TC),
                Tz = expf(tv.z * (float)TC), Tw = expf(tv.w * (float)TC);
    const float fQ = (float)(TC * P);
    const float Qx = expf(tv.x * fQ), Qy = expf(tv.y * fQ),
                Qz = expf(tv.z * fQ), Qw = expf(tv.w * fQ);

    // ---- phase 1: chunk into registers, local zero-carry scan ----
    const size_t base = (size_t)c * TC * HV + t;
    float4 buf[TC];
#pragma unroll
    for (int i = 0; i < TC; ++i)
        buf[i] = ntload(&xv[base + (size_t)i * HV]);   // 16 indep 16B loads

    float4 s = make_float4(0.f, 0.f, 0.f, 0.f);
#pragma unroll
    for (int i = 0; i < TC; ++i) {
        s.x = fmaf(lx, s.x, buf[i].x);
        s.y = fmaf(ly, s.y, buf[i].y);
        s.z = fmaf(lz, s.z, buf[i].z);
        s.w = fmaf(lw, s.w, buf[i].w);
        buf[i] = s;
    }
    ends[(size_t)c * HV + t] = s;

    cg::this_grid().sync();

    // ---- phase 2: partition aggregates (first NP blocks only) ----
    if (c < NP) {
        const float4* ep = ends + (size_t)c * P * HV + t;
        float4 a = make_float4(0.f, 0.f, 0.f, 0.f);
#pragma unroll
        for (int j0 = 0; j0 < P; j0 += 8) {
            float4 v[8];
#pragma unroll
            for (int j = 0; j < 8; ++j)
                v[j] = ep[(size_t)(j0 + j) * HV];
#pragma unroll
            for (int j = 0; j < 8; ++j) {
                a.x = fmaf(Tx, a.x, v[j].x);
                a.y = fmaf(Ty, a.y, v[j].y);
                a.z = fmaf(Tz, a.z, v[j].z);
                a.w = fmaf(Tw, a.w, v[j].w);
            }
        }
        pa[(size_t)c * HV + t] = a;
    }

    cg::this_grid().sync();

    // ---- phase 3: carry, then output from registers ----
    const int p = c / P;
    const int r = c % P;

    float4 carry = make_float4(0.f, 0.f, 0.f, 0.f);
    for (int q0 = 0; q0 < p; q0 += 8) {          // partition-level scan (L2-hot)
        const int n = p - q0;
        float4 v[8];
#pragma unroll
        for (int j = 0; j < 8; ++j)
            if (j < n) v[j] = pa[(size_t)(q0 + j) * HV + t];
#pragma unroll
        for (int j = 0; j < 8; ++j) {
            if (j < n) {
                carry.x = fmaf(Qx, carry.x, v[j].x);
                carry.y = fmaf(Qy, carry.y, v[j].y);
                carry.z = fmaf(Qz, carry.z, v[j].z);
                carry.w = fmaf(Qw, carry.w, v[j].w);
            }
        }
    }
    {
        const float4* ep = ends + (size_t)p * P * HV + t;
        for (int j0 = 0; j0 < r; j0 += 8) {      // in-partition advance
            const int n = r - j0;
            float4 v[8];
#pragma unroll
            for (int j = 0; j < 8; ++j)
                if (j < n) v[j] = ep[(size_t)(j0 + j) * HV];
#pragma unroll
            for (int j = 0; j < 8; ++j) {
                if (j < n) {
                    carry.x = fmaf(Tx, carry.x, v[j].x);
                    carry.y = fmaf(Ty, carry.y, v[j].y);
                    carry.z = fmaf(Tz, carry.z, v[j].z);
                    carry.w = fmaf(Tw, carry.w, v[j].w);
                }
            }
        }
    }

    float4 pm = make_float4(lx, ly, lz, lw);
    nt4* yn = (nt4*)yv;
#pragma unroll
    for (int i = 0; i < TC; ++i) {
        nt4 o = { fmaf(pm.x, carry.x, buf[i].x),
                  fmaf(pm.y, carry.y, buf[i].y),
                  fmaf(pm.z, carry.z, buf[i].z),
                  fmaf(pm.w, carry.w, buf[i].w) };
        __builtin_nontemporal_store(o, &yn[base + (size_t)i * HV]);
        pm.x *= lx; pm.y *= ly; pm.z *= lz; pm.w *= lw;
    }
}

// ---------------- R6 feed-forward fallback ----------------

__global__ __launch_bounds__(256)
void li_ends(const float4* __restrict__ xv, const float4* __restrict__ tauv,
             float4* __restrict__ ends, int HV) {
    const int t = threadIdx.x;
    const int c = blockIdx.x;
    const float4 tv = tauv[t];
    const float lx = expf(tv.x), ly = expf(tv.y),
                lz = expf(tv.z), lw = expf(tv.w);
    const float4* xp = xv + (size_t)c * TC * HV + t;
    float4 buf[TC];
#pragma unroll
    for (int i = 0; i < TC; ++i)
        buf[i] = xp[(size_t)i * HV];
    float4 s = make_float4(0.f, 0.f, 0.f, 0.f);
#pragma unroll
    for (int i = 0; i < TC; ++i) {
        s.x = fmaf(lx, s.x, buf[i].x);
        s.y = fmaf(ly, s.y, buf[i].y);
        s.z = fmaf(lz, s.z, buf[i].z);
        s.w = fmaf(lw, s.w, buf[i].w);
    }
    ends[(size_t)c * HV + t] = s;
}

__global__ __launch_bounds__(256)
void li_pagg(const float4* __restrict__ ends, const float4* __restrict__ tauv,
             float4* __restrict__ pa, int HV) {
    const int gid = blockIdx.x * 256 + threadIdx.x;
    const int t = gid % HV;
    const int p = gid / HV;
    const float4 tv = tauv[t];
    const float Tx = expf(tv.x * (float)TC), Ty = expf(tv.y * (float)TC),
                Tz = expf(tv.z * (float)TC), Tw = expf(tv.w * (float)TC);
    const float4* ep = ends + (size_t)p * P * HV + t;
    float4 buf[P];
#pragma unroll
    for (int j = 0; j < P; ++j)
        buf[j] = ep[(size_t)j * HV];
    float4 s = make_float4(0.f, 0.f, 0.f, 0.f);
#pragma unroll
    for (int j = 0; j < P; ++j) {
        s.x = fmaf(Tx, s.x, buf[j].x);
        s.y = fmaf(Ty, s.y, buf[j].y);
        s.z = fmaf(Tz, s.z, buf[j].z);
        s.w = fmaf(Tw, s.w, buf[j].w);
    }
    pa[(size_t)p * HV + t] = s;
}

__global__ __launch_bounds__(256)
void li_pscan(float4* __restrict__ pa, const float4* __restrict__ tauv,
              int HV, int NP) {
    const int t = threadIdx.x;
    const float4 tv = tauv[t];
    const float fP = (float)(P * TC);
    const float Px = expf(tv.x * fP), Py = expf(tv.y * fP),
                Pz = expf(tv.z * fP), Pw = expf(tv.w * fP);
    float4 c = make_float4(0.f, 0.f, 0.f, 0.f);
    for (int p0 = 0; p0 < NP; p0 += 16) {
        float4 v[16];
#pragma unroll
        for (int j = 0; j < 16; ++j)
            v[j] = pa[(size_t)(p0 + j) * HV + t];
#pragma unroll
        for (int j = 0; j < 16; ++j) {
            const float4 a = v[j];
            v[j] = c;
            c.x = fmaf(Px, c.x, a.x);
            c.y = fmaf(Py, c.y, a.y);
            c.z = fmaf(Pz, c.z, a.z);
            c.w = fmaf(Pw, c.w, a.w);
        }
#pragma unroll
        for (int j = 0; j < 16; ++j)
            pa[(size_t)(p0 + j) * HV + t] = v[j];
    }
}

__global__ __launch_bounds__(256)
void li_out(const float4* __restrict__ xv, const float4* __restrict__ tauv,
            const float4* __restrict__ ends, const float4* __restrict__ pc,
            float4* __restrict__ yv, int HV) {
    const int t = threadIdx.x;
    const int c = blockIdx.x;
    const int p = c / P;
    const int r = c % P;
    const float4 tv = tauv[t];
    const float lx = expf(tv.x), ly = expf(tv.y),
                lz = expf(tv.z), lw = expf(tv.w);
    const float Tx = expf(tv.x * (float)TC), Ty = expf(tv.y * (float)TC),
                Tz = expf(tv.z * (float)TC), Tw = expf(tv.w * (float)TC);
    float4 carry = pc[(size_t)p * HV + t];
    {
        float4 v[P - 1];
        const float4* ep = ends + (size_t)p * P * HV + t;
#pragma unroll
        for (int j = 0; j < P - 1; ++j)
            if (j < r) v[j] = ep[(size_t)j * HV];
#pragma unroll
        for (int j = 0; j < P - 1; ++j) {
            if (j < r) {
                carry.x = fmaf(Tx, carry.x, v[j].x);
                carry.y = fmaf(Ty, carry.y, v[j].y);
                carry.z = fmaf(Tz, carry.z, v[j].z);
                carry.w = fmaf(Tw, carry.w, v[j].w);
            }
        }
    }
    const size_t base = (size_t)c * TC * HV + t;
    float4 buf[TC];
#pragma unroll
    for (int i = 0; i < TC; ++i)
        buf[i] = xv[base + (size_t)i * HV];
    float4 s = carry;
#pragma unroll
    for (int i = 0; i < TC; ++i) {
        s.x = fmaf(lx, s.x, buf[i].x);
        s.y = fmaf(ly, s.y, buf[i].y);
        s.z = fmaf(lz, s.z, buf[i].z);
        s.w = fmaf(lw, s.w, buf[i].w);
        buf[i] = s;
    }
    nt4* yn = (nt4*)yv;
#pragma unroll
    for (int i = 0; i < TC; ++i) {
        nt4 o = { buf[i].x, buf[i].y, buf[i].z, buf[i].w };
        __builtin_nontemporal_store(o, &yn[base + (size_t)i * HV]);
    }
}

extern "C" void kernel_launch(void* const* d_in, const int* in_sizes, int n_in,
                              void* d_out, int out_size, void* d_ws, size_t ws_size,
                              hipStream_t stream) {
    const float* x   = (const float*)d_in[0];
    const float* tau = (const float*)d_in[1];
    float* y = (float*)d_out;

    const int H  = in_sizes[1];        // 1024
    const int L  = in_sizes[0] / H;    // 16384
    const int C  = L / TC;             // 1024
    const int NP = C / P;              // 64
    const int HV = H / 4;              // 256 float4 columns

    float4* ends = (float4*)d_ws;                       // C*HV float4 = 4 MB
    float4* pa   = ends + (size_t)C * HV;               // NP*HV float4 = 64 KB

    const float4* xv   = (const float4*)x;
    const float4* tauv = (const float4*)tau;
    float4*       yv   = (float4*)y;

    // Cooperative path requires all C blocks co-resident (4 blocks/CU).
    int blocksPerCU = 0;
    hipError_t qe = hipOccupancyMaxActiveBlocksPerMultiprocessor(
        &blocksPerCU, li_coop, 256, 0);

    bool coop_ok = false;
    if (qe == hipSuccess && blocksPerCU >= 4) {
        void* args[] = { (void*)&xv, (void*)&tauv, (void*)&yv,
                         (void*)&ends, (void*)&pa, (void*)&HV, (void*)&NP };
        hipError_t le = hipLaunchCooperativeKernel(
            li_coop, dim3(C), dim3(256), args, 0u, stream);
        coop_ok = (le == hipSuccess);
    }

    if (!coop_ok) {
        li_ends <<<dim3(C),             dim3(256), 0, stream>>>(xv, tauv, ends, HV);
        li_pagg <<<dim3(NP * HV / 256), dim3(256), 0, stream>>>(ends, tauv, pa, HV);
        li_pscan<<<dim3(1),             dim3(256), 0, stream>>>(pa, tauv, HV, NP);
        li_out  <<<dim3(C),             dim3(256), 0, stream>>>(xv, tauv, ends, pa,
                                                                yv, HV);
    }
}